// Round 15
// baseline (183.581 us; speedup 1.0000x reference)
//
#include <hip/hip_runtime.h>
#include <hip/hip_bf16.h>
#include <stdint.h>

// ---------------- types / helpers ----------------
typedef __bf16 bf16x8 __attribute__((ext_vector_type(8)));
typedef __bf16 bf16x2 __attribute__((ext_vector_type(2)));
typedef unsigned short u16x8 __attribute__((ext_vector_type(8)));
typedef float f32x4 __attribute__((ext_vector_type(4)));
typedef float f32x16 __attribute__((ext_vector_type(16)));
typedef uint32_t u32x4 __attribute__((ext_vector_type(4)));

#define DMODEL 768
#define NSEQ   2048
#define BATCH  2
#define NHEAD  12
#define HDIM   64
#define HIDDEN 3072
#define PROWS  (BATCH * NHEAD * NSEQ)   // 49152 attention rows
#define NZ     4                        // split-KV factor
// 0.125 * log2(e): fold softmax scale AND exp->exp2 conversion into Q
#define QSCALE 0.18033688011112042f
#define MCONST 16.0f                    // constant softmax max (scores << 16)
#define PMASKED 1.52587890625e-05f      // exp2(0 - 16): each zero-pad key's P

__device__ __forceinline__ uint16_t f2bf(float f) {
  __bf16 h = (__bf16)f;
  return __builtin_bit_cast(uint16_t, h);
}
__device__ __forceinline__ float bf2f(uint16_t u) {
  uint32_t x = (uint32_t)u << 16;
  return __builtin_bit_cast(float, x);
}
__device__ __forceinline__ bf16x8 ldb8(const uint16_t* p) {
  return __builtin_bit_cast(bf16x8, *reinterpret_cast<const u16x8*>(p));
}
// tanh-form GELU via native exp2
__device__ __forceinline__ float gelu_f(float x) {
  float u = x * (1.0f + 0.044715f * x * x);
  float e = fminf(u * 2.302208545f, 80.0f);   // 2*0.79788456*log2(e)
  float t = exp2f(e);
  return x * t / (t + 1.0f);
}
// XCD-aware bijective block swizzle (nwg divisible by 8 for all launches)
__device__ __forceinline__ void xcd_swz(int& bx, int& by) {
  const int gx = gridDim.x;
  const int nwg = gx * gridDim.y;
  const int orig = blockIdx.y * gx + blockIdx.x;
  const int wg = (orig & 7) * (nwg >> 3) + (orig >> 3);
  bx = wg % gx;
  by = wg / gx;
}

using as1_void = __attribute__((address_space(1))) const void;
using as3_void = __attribute__((address_space(3))) void;
__device__ __forceinline__ void gload16(const uint16_t* src, uint16_t* lds) {
  __builtin_amdgcn_global_load_lds((as1_void*)src, (as3_void*)lds, 16, 0, 0);
}
#define MEMFENCE asm volatile("" ::: "memory")

// ---------------- fused fp32 -> bf16 casts ----------------
#define N_QKVW  (3 * DMODEL * DMODEL)
#define N_PROJW (DMODEL * DMODEL)
#define N_FC1W  (HIDDEN * DMODEL)
#define N_FC2W  (DMODEL * HIDDEN)
__global__ __launch_bounds__(256) void cvt4_kernel(const float* __restrict__ s0,
                                                   const float* __restrict__ s1,
                                                   const float* __restrict__ s2,
                                                   const float* __restrict__ s3,
                                                   uint16_t* __restrict__ d0,
                                                   uint16_t* __restrict__ d1,
                                                   uint16_t* __restrict__ d2,
                                                   uint16_t* __restrict__ d3) {
  int i4 = (blockIdx.x * 256 + threadIdx.x) * 4;
  const float* s;
  uint16_t* d;
  if (i4 < N_QKVW) { s = s0 + i4; d = d0 + i4; }
  else if (i4 < N_QKVW + N_PROJW) { int j = i4 - N_QKVW; s = s1 + j; d = d1 + j; }
  else if (i4 < N_QKVW + N_PROJW + N_FC1W) { int j = i4 - N_QKVW - N_PROJW; s = s2 + j; d = d2 + j; }
  else { int j = i4 - N_QKVW - N_PROJW - N_FC1W; s = s3 + j; d = d3 + j; }
  float4 v = *reinterpret_cast<const float4*>(s);
  ushort4 o;
  o.x = f2bf(v.x); o.y = f2bf(v.y); o.z = f2bf(v.z); o.w = f2bf(v.w);
  *reinterpret_cast<ushort4*>(d) = o;
}

// ---------------- qkv bias assembly ----------------
__global__ __launch_bounds__(256) void bias_kernel(const float* __restrict__ qb,
                                                   const float* __restrict__ vb,
                                                   float* __restrict__ out) {
  int j = blockIdx.x * 256 + threadIdx.x;
  if (j < 3 * DMODEL) {
    float v = 0.f;
    if (j < DMODEL) v = qb[j];
    else if (j >= 2 * DMODEL) v = vb[j - 2 * DMODEL];
    out[j] = v;
  }
}

// ---------------- mask prefix-sum: pos[b][n] (exclusive), nk[b] ----------------
__global__ __launch_bounds__(256) void scan_kernel(const int* __restrict__ mask,
                                                   int* __restrict__ pos,
                                                   int* __restrict__ nk) {
  const int b = blockIdx.x;
  const int tid = threadIdx.x;
  const int lane = tid & 63, w = tid >> 6;
  __shared__ int wsum[4];
  int base = 0;
  for (int c = 0; c < NSEQ; c += 256) {
    int m = (mask[b * NSEQ + c + tid] != 0);
    unsigned long long bits = __ballot(m);
    int lanepre = __popcll(bits & ((1ull << lane) - 1ull));
    if (lane == 0) wsum[w] = __popcll(bits);
    __syncthreads();
    int wpre = 0;
#pragma unroll
    for (int i = 0; i < 4; ++i) wpre += (i < w) ? wsum[i] : 0;
    pos[b * NSEQ + c + tid] = base + wpre + lanepre;
    int total = wsum[0] + wsum[1] + wsum[2] + wsum[3];
    __syncthreads();
    base += total;
  }
  if (tid == 0) nk[b] = base;
}

// ---------------- layernorm: fp32 in -> bf16 out ----------------
__global__ __launch_bounds__(256) void ln_kernel(const float* __restrict__ x,
                                                 const float* __restrict__ g,
                                                 const float* __restrict__ bt,
                                                 uint16_t* __restrict__ out) {
  const int row = blockIdx.x;
  const int t = threadIdx.x;
  const float* xr = x + (size_t)row * DMODEL;
  float v0 = xr[t], v1 = xr[t + 256], v2 = xr[t + 512];
  float s = v0 + v1 + v2;
  float q = v0 * v0 + v1 * v1 + v2 * v2;
  for (int off = 32; off >= 1; off >>= 1) {
    s += __shfl_xor(s, off);
    q += __shfl_xor(q, off);
  }
  __shared__ float ss[4], sq[4];
  int w = t >> 6;
  if ((t & 63) == 0) { ss[w] = s; sq[w] = q; }
  __syncthreads();
  s = ss[0] + ss[1] + ss[2] + ss[3];
  q = sq[0] + sq[1] + sq[2] + sq[3];
  const float mean = s * (1.0f / DMODEL);
  const float var = q * (1.0f / DMODEL) - mean * mean;
  const float rstd = rsqrtf(var + 1e-5f);
  uint16_t* orow = out + (size_t)row * DMODEL;
  orow[t]       = f2bf((v0 - mean) * rstd * g[t]       + bt[t]);
  orow[t + 256] = f2bf((v1 - mean) * rstd * g[t + 256] + bt[t + 256]);
  orow[t + 512] = f2bf((v2 - mean) * rstd * g[t + 512] + bt[t + 512]);
}

// ------------- GEMM A: 128x128 block, 4 waves x (64x64), dbuf counted-vmcnt ----
// XCD-swizzled. MODE 0: QKV gemm, fused COMPACTING prep:
//   sect 0 (Q): q_bf = (acc+bias)*QSCALE, row-major [4096][768]
//   sect 1 (K): km[b*NSEQ + pos[n]] = acc+bias  (valid keys only, compacted)
//   sect 2 (V): vt[bh][d][pos[n]]   = acc+bias  (valid keys only, compacted)
// km/vt pre-zeroed by hipMemsetAsync -> compacted tail stays zero.
// MODE 2: out bf16 = gelu(acc + bias)  (fc1)
template <int MODE>
__global__ __launch_bounds__(256, 3) void gemm128(const uint16_t* __restrict__ A,
                                                  const uint16_t* __restrict__ W,
                                                  const float* __restrict__ bias,
                                                  void* __restrict__ outp,
                                                  uint16_t* __restrict__ km,
                                                  uint16_t* __restrict__ vt,
                                                  const int* __restrict__ amask,
                                                  const int* __restrict__ pos,
                                                  int M, int N, int K) {
  __shared__ uint16_t As[2][128 * 32];
  __shared__ uint16_t Bs[2][128 * 32];
  const int tid = threadIdx.x;
  const int lane = tid & 63;
  const int w = tid >> 6;
  const int wr = w >> 1, wc = w & 1;
  int bx, by;
  xcd_swz(bx, by);
  const int row0 = by * 128;
  const int col0 = bx * 128;
  const int lr = lane & 15;
  const int g = lane >> 4;

  const int o0 = w * 1024 + lane * 16;
  const int o1 = o0 + 4096;
  const int r0s = o0 >> 6, c0s = (o0 & 63) >> 1;
  const int r1s = o1 >> 6, c1s = (o1 & 63) >> 1;
  const int l0 = (w * 1024) >> 1;
  const int l1 = l0 + 2048;
  const uint16_t* Abase = A + (size_t)row0 * K;
  const uint16_t* Wbase = W + (size_t)col0 * K;

  auto stage = [&](int kt) {
    uint16_t* Ad = &As[kt & 1][0];
    uint16_t* Bd = &Bs[kt & 1][0];
    const int kk = kt * 32;
    gload16(Abase + (size_t)r0s * K + kk + c0s, Ad + l0);
    gload16(Abase + (size_t)r1s * K + kk + c1s, Ad + l1);
    gload16(Wbase + (size_t)r0s * K + kk + c0s, Bd + l0);
    gload16(Wbase + (size_t)r1s * K + kk + c1s, Bd + l1);
  };

  f32x4 acc[4][4] = {};
  const int nt = K >> 5;
  stage(0);
  for (int kt = 0; kt < nt; ++kt) {
    if (kt + 1 < nt) {
      stage(kt + 1);
      asm volatile("s_waitcnt vmcnt(4)" ::: "memory");
    } else {
      asm volatile("s_waitcnt vmcnt(0)" ::: "memory");
    }
    __builtin_amdgcn_s_barrier();
    MEMFENCE;
    const uint16_t* Ab = &As[kt & 1][0];
    const uint16_t* Bb = &Bs[kt & 1][0];
    bf16x8 a[4], b[4];
#pragma unroll
    for (int m = 0; m < 4; ++m) a[m] = ldb8(Ab + (wr * 64 + m * 16 + lr) * 32 + g * 8);
#pragma unroll
    for (int n = 0; n < 4; ++n) b[n] = ldb8(Bb + (wc * 64 + n * 16 + lr) * 32 + g * 8);
#pragma unroll
    for (int m = 0; m < 4; ++m)
#pragma unroll
      for (int n = 0; n < 4; ++n)
        acc[m][n] = __builtin_amdgcn_mfma_f32_16x16x32_bf16(a[m], b[n], acc[m][n], 0, 0, 0);
    MEMFENCE;
    __builtin_amdgcn_s_barrier();
  }

  if constexpr (MODE == 0) {
    const int sect = col0 / DMODEL;   // block-uniform: 0=Q, 1=K, 2=V
    const int bb = row0 >> 11;        // batch (block never crosses)
    const int* mrow = amask + bb * NSEQ;
    const int* prow = pos + bb * NSEQ;
#pragma unroll
    for (int m = 0; m < 4; ++m) {
      int row = row0 + wr * 64 + m * 16 + g * 4;
      int nn = row & 2047;
      int mk[4], ps[4];
#pragma unroll
      for (int ri = 0; ri < 4; ++ri) { mk[ri] = mrow[nn + ri]; ps[ri] = prow[nn + ri]; }
#pragma unroll
      for (int n = 0; n < 4; ++n) {
        int col = col0 + wc * 64 + n * 16 + lr;
        float bv = bias[col];
        if (sect == 0) {
#pragma unroll
          for (int ri = 0; ri < 4; ++ri)
            ((uint16_t*)outp)[(size_t)(row + ri) * DMODEL + col] =
                f2bf((acc[m][n][ri] + bv) * QSCALE);
        } else if (sect == 1) {
          int kc = col - DMODEL;
#pragma unroll
          for (int ri = 0; ri < 4; ++ri)
            if (mk[ri])
              km[(size_t)(bb * NSEQ + ps[ri]) * DMODEL + kc] = f2bf(acc[m][n][ri] + bv);
        } else {
          int vc = col - 2 * DMODEL;
          int hh2 = vc >> 6, dd = vc & 63;
          const size_t vbase = (size_t)((bb * NHEAD + hh2) * 64 + dd) * NSEQ;
#pragma unroll
          for (int ri = 0; ri < 4; ++ri)
            if (mk[ri]) vt[vbase + ps[ri]] = f2bf(acc[m][n][ri] + bv);
        }
      }
    }
  } else {
#pragma unroll
    for (int m = 0; m < 4; ++m) {
      int row = row0 + wr * 64 + m * 16 + g * 4;
#pragma unroll
      for (int n = 0; n < 4; ++n) {
        int col = col0 + wc * 64 + n * 16 + lr;
        float bv = bias[col];
#pragma unroll
        for (int ri = 0; ri < 4; ++ri) {
          float val = acc[m][n][ri] + bv;
          ((uint16_t*)outp)[(size_t)(row + ri) * N + col] = f2bf(gelu_f(val));
        }
      }
    }
  }
}

// ------------- GEMM B v2: 64x64 tile, BK=64, 4 waves, XCD-swizzled -------------
__global__ __launch_bounds__(256, 3) void gemm64(const uint16_t* __restrict__ A,
                                                 const uint16_t* __restrict__ W,
                                                 const float* __restrict__ bias,
                                                 float* __restrict__ outp,
                                                 const float* __restrict__ resid,
                                                 const float* __restrict__ gamma,
                                                 int M, int N, int K) {
  __shared__ uint16_t As[2][64 * 64];
  __shared__ uint16_t Bs[2][64 * 64];
  const int tid = threadIdx.x;
  const int lane = tid & 63;
  const int w = tid >> 6;
  const int wr = w >> 1, wc = w & 1;
  int bx, by;
  xcd_swz(bx, by);
  const int row0 = by * 64;
  const int col0 = bx * 64;
  const int lr = lane & 15;
  const int g = lane >> 4;

  const int srow = tid >> 3;
  const int schunk = tid & 7;
  const uint16_t* Abase = A + (size_t)row0 * K;
  const uint16_t* Wbase = W + (size_t)col0 * K;

  auto stage = [&](int kt) {
    uint16_t* Ad = &As[kt & 1][0];
    uint16_t* Bd = &Bs[kt & 1][0];
    const int kk = kt * 64;
#pragma unroll
    for (int i = 0; i < 2; ++i) {
      const int row = i * 32 + srow;
      const int sc = (schunk ^ (row & 7)) * 8;
      gload16(Abase + (size_t)row * K + kk + sc, Ad + i * 2048 + w * 512);
      gload16(Wbase + (size_t)row * K + kk + sc, Bd + i * 2048 + w * 512);
    }
  };

  f32x4 acc[2][2] = {};
  const int nt = K >> 6;
  stage(0);
  for (int kt = 0; kt < nt; ++kt) {
    if (kt + 1 < nt) {
      stage(kt + 1);
      asm volatile("s_waitcnt vmcnt(4)" ::: "memory");
    } else {
      asm volatile("s_waitcnt vmcnt(0)" ::: "memory");
    }
    __builtin_amdgcn_s_barrier();
    MEMFENCE;
    const uint16_t* Ab = &As[kt & 1][0];
    const uint16_t* Bb = &Bs[kt & 1][0];
#pragma unroll
    for (int kk = 0; kk < 2; ++kk) {
      bf16x8 a[2], bf[2];
#pragma unroll
      for (int m = 0; m < 2; ++m) {
        const int row = wr * 32 + m * 16 + lr;
        a[m] = ldb8(Ab + row * 64 + (((kk * 4 + g) ^ (row & 7)) * 8));
      }
#pragma unroll
      for (int n = 0; n < 2; ++n) {
        const int row = wc * 32 + n * 16 + lr;
        bf[n] = ldb8(Bb + row * 64 + (((kk * 4 + g) ^ (row & 7)) * 8));
      }
#pragma unroll
      for (int m = 0; m < 2; ++m)
#pragma unroll
        for (int n = 0; n < 2; ++n)
          acc[m][n] = __builtin_amdgcn_mfma_f32_16x16x32_bf16(a[m], bf[n], acc[m][n], 0, 0, 0);
    }
    MEMFENCE;
    __builtin_amdgcn_s_barrier();
  }

#pragma unroll
  for (int m = 0; m < 2; ++m) {
    int row = row0 + wr * 32 + m * 16 + g * 4;
#pragma unroll
    for (int n = 0; n < 2; ++n) {
      int col = col0 + wc * 32 + n * 16 + lr;
      float bv = bias[col];
      float gv = gamma[col];
#pragma unroll
      for (int ri = 0; ri < 4; ++ri) {
        float val = acc[m][n][ri] + bv;
        size_t idx = (size_t)(row + ri) * N + col;
        outp[idx] = resid[idx] + gv * val;
      }
    }
  }
}

// ---------------- flash attention v11: COMPACTED keys, quad-buffer -------------
// grid (24, 8, 4): 8 waves x 32 q-rows. Keys compacted to nk[b] (~50% of 2048
// with random mask) -> tiles ~halve. Dynamic-trip 4-buffer pipeline, counted
// vmcnt. Zero-padded tail keys contribute P = 2^-16 (V = 0); corrected exactly
// via pads count. Constant-max softmax (m = 16).
__global__ __launch_bounds__(512, 4) void attn_kernel(const uint16_t* __restrict__ qb_,
                                                      const uint16_t* __restrict__ km,
                                                      const uint16_t* __restrict__ vt,
                                                      const int* __restrict__ nkarr,
                                                      uint16_t* __restrict__ po,
                                                      float* __restrict__ pml) {
  __shared__ uint16_t Kb[4][64 * 64];
  __shared__ uint16_t Vb[4][64 * 64];
  const int tid = threadIdx.x;
  const int lane = tid & 63;
  const int w = tid >> 6;            // 8 waves
  const int bh = blockIdx.x;
  const int b = bh / NHEAD, hd = bh % NHEAD;
  const int z = blockIdx.z;
  const int q0 = blockIdx.y * 256 + w * 32;
  const int l31 = lane & 31;
  const int hh = lane >> 5;

  const int NKb = nkarr[b];
  const int NTt = (NKb + 63) >> 6;          // total key tiles
  const int TPZ = (NTt + NZ - 1) >> 2;      // tiles per z-chunk
  const int s0 = (z * TPZ < NTt) ? z * TPZ : NTt;
  int e0 = s0 + TPZ; if (e0 > NTt) e0 = NTt;
  const int nt = e0 - s0;

  bf16x8 qa[4];
  const uint16_t* qptr = qb_ + (size_t)(b * NSEQ + q0 + l31) * DMODEL + hd * HDIM + hh * 8;
#pragma unroll
  for (int dblk = 0; dblk < 4; ++dblk) qa[dblk] = ldb8(qptr + dblk * 16);

  const uint16_t* kmb = km + (size_t)b * NSEQ * DMODEL + hd * HDIM;
  const uint16_t* vtb = vt + (size_t)bh * HDIM * NSEQ;

  const int srow = tid >> 3;                      // 0..63
  const int sxor = ((tid & 7) ^ (srow & 7)) * 8;  // pre-swizzled source chunk
  auto stage = [&](int t) {
    const int pb = t & 3;
    const int k0 = t * 64;
    gload16(kmb + (size_t)(k0 + srow) * DMODEL + sxor, &Kb[pb][w * 512]);
    gload16(vtb + (size_t)srow * NSEQ + k0 + sxor, &Vb[pb][w * 512]);
  };

  u16x8 ones_u;
#pragma unroll
  for (int e = 0; e < 8; ++e) ones_u[e] = 0x3F80;   // bf16 1.0
  const bf16x8 ones = __builtin_bit_cast(bf16x8, ones_u);

  f32x16 oacc[2] = {};
  f32x16 lacc = {};

  if (nt > 0) stage(s0);
  if (nt > 1) stage(s0 + 1);
  if (nt > 2) stage(s0 + 2);
  for (int i = 0; i < nt; ++i) {
    const int ahead = nt - 1 - i;
    if (ahead >= 2) {
      asm volatile("s_waitcnt vmcnt(4)" ::: "memory");
    } else if (ahead == 1) {
      asm volatile("s_waitcnt vmcnt(2)" ::: "memory");
    } else {
      asm volatile("s_waitcnt vmcnt(0)" ::: "memory");
    }
    __builtin_amdgcn_s_barrier();     // all waves' stage(s0+i) complete
    MEMFENCE;
    if (i + 3 < nt) stage(s0 + i + 3);
    const uint16_t* Kbp = &Kb[(s0 + i) & 3][0];
    const uint16_t* Vbp = &Vb[(s0 + i) & 3][0];

    // S^T[k][q] = mfma(K, Q); lane = q, regs = k
    f32x16 st[2];
    __builtin_amdgcn_s_setprio(1);
#pragma unroll
    for (int kblk = 0; kblk < 2; ++kblk) {
      f32x16 acc = {};
      const uint16_t* kr = Kbp + (kblk * 32 + l31) * 64;
#pragma unroll
      for (int dblk = 0; dblk < 4; ++dblk) {
        bf16x8 kf = ldb8(kr + ((dblk * 2 + hh) ^ (l31 & 7)) * 8);
        acc = __builtin_amdgcn_mfma_f32_32x32x16_bf16(kf, qa[dblk], acc, 0, 0, 0);
      }
      st[kblk] = acc;
    }
    __builtin_amdgcn_s_setprio(0);

    // P = exp2(s - 16), pack to bf16 pairs
    uint32_t pk[2][8];
#pragma unroll
    for (int kblk = 0; kblk < 2; ++kblk)
#pragma unroll
      for (int wn = 0; wn < 8; ++wn) {
        float e0x = exp2f(st[kblk][2 * wn] - MCONST);
        float e1x = exp2f(st[kblk][2 * wn + 1] - MCONST);
        bf16x2 pr = {(__bf16)e0x, (__bf16)e1x};
        pk[kblk][wn] = __builtin_bit_cast(uint32_t, pr);
      }

    // gather PV A-frags
    bf16x8 af[4];
#pragma unroll
    for (int kb16 = 0; kb16 < 4; ++kb16) {
      const int kblk = kb16 >> 1;
      const int a4 = (kb16 & 1) * 4;
      uint32_t ow0 = hh ? pk[kblk][a4 + 2] : pk[kblk][a4 + 0];
      uint32_t ow1 = hh ? pk[kblk][a4 + 3] : pk[kblk][a4 + 1];
      uint32_t gv0 = hh ? pk[kblk][a4 + 0] : pk[kblk][a4 + 2];
      uint32_t gv1 = hh ? pk[kblk][a4 + 1] : pk[kblk][a4 + 3];
      uint32_t sw0 = (uint32_t)__shfl_xor((int)gv0, 32);
      uint32_t sw1 = (uint32_t)__shfl_xor((int)gv1, 32);
      u32x4 afu;
      afu[0] = hh ? sw0 : ow0;
      afu[1] = hh ? sw1 : ow1;
      afu[2] = hh ? ow0 : sw0;
      afu[3] = hh ? ow1 : sw1;
      af[kb16] = __builtin_bit_cast(bf16x8, afu);
    }

    __builtin_amdgcn_s_setprio(1);
#pragma unroll
    for (int dblk = 0; dblk < 2; ++dblk) {
      const uint16_t* vr = Vbp + (dblk * 32 + l31) * 64;
#pragma unroll
      for (int kb16 = 0; kb16 < 4; ++kb16) {
        bf16x8 vf = ldb8(vr + ((kb16 * 2 + hh) ^ (l31 & 7)) * 8);
        oacc[dblk] = __builtin_amdgcn_mfma_f32_32x32x16_bf16(af[kb16], vf, oacc[dblk], 0, 0, 0);
      }
    }
#pragma unroll
    for (int kb16 = 0; kb16 < 4; ++kb16)   // row-sum on matrix pipe
      lacc = __builtin_amdgcn_mfma_f32_32x32x16_bf16(af[kb16], ones, lacc, 0, 0, 0);
    __builtin_amdgcn_s_setprio(0);
    MEMFENCE;
  }

  // zero-pad correction: processed nt*64 keys, valid = min(e0*64,NK) - s0*64
  int vend = e0 * 64; if (vend > NKb) vend = NKb;
  int valid = vend - s0 * 64; if (valid < 0) valid = 0;
  const int pads = nt * 64 - valid;
  const float cntf = (float)pads * PMASKED;

  uint16_t* ob = po + ((size_t)z * PROWS + (size_t)bh * NSEQ + q0) * 64;
#pragma unroll
  for (int r = 0; r < 16; ++r) {
    const int qrow = (r & 3) + 8 * (r >> 2) + 4 * hh;
#pragma unroll
    for (int dblk = 0; dblk < 2; ++dblk)
      ob[(size_t)qrow * 64 + dblk * 32 + l31] = f2bf(oacc[dblk][r]);
  }
  if (l31 == 0) {
#pragma unroll
    for (int r = 0; r < 16; ++r) {
      const int qrow = (r & 3) + 8 * (r >> 2) + 4 * hh;
      pml[(size_t)z * PROWS + (size_t)bh * NSEQ + q0 + qrow] = lacc[r] - cntf;
    }
  }
}

// ---------------- merge 4 split-KV partials -> o_bf ----------------------------
__global__ __launch_bounds__(256) void merge_kernel(const uint16_t* __restrict__ po,
                                                    const float* __restrict__ pml,
                                                    uint16_t* __restrict__ o) {
  int gid = blockIdx.x * 256 + threadIdx.x;   // 393216 = 49152 rows x 8 chunks
  int row = gid >> 3;
  int c0 = (gid & 7) * 8;
  float L = 0.f;
#pragma unroll
  for (int zz = 0; zz < NZ; ++zz) L += pml[(size_t)zz * PROWS + row];
  float inv = L > 0.f ? 1.f / L : 0.f;
  float sum[8] = {};
#pragma unroll
  for (int zz = 0; zz < NZ; ++zz) {
    u16x8 a = *reinterpret_cast<const u16x8*>(po + ((size_t)zz * PROWS + row) * 64 + c0);
#pragma unroll
    for (int e = 0; e < 8; ++e) sum[e] += bf2f(a[e]);
  }
  int bh = row >> 11, q = row & 2047;
  int bb = bh / NHEAD, hh = bh % NHEAD;
  uint16_t* op = o + ((size_t)(bb * NSEQ + q) * DMODEL + hh * HDIM + c0);
  u16x8 outv;
#pragma unroll
  for (int e = 0; e < 8; ++e) outv[e] = f2bf(sum[e] * inv);
  *reinterpret_cast<u16x8*>(op) = outv;
}

// ---------------- host ----------------
extern "C" void kernel_launch(void* const* d_in, const int* in_sizes, int n_in,
                              void* d_out, int out_size, void* d_ws, size_t ws_size,
                              hipStream_t stream) {
  const float* x      = (const float*)d_in[0];
  const int*   amask  = (const int*)d_in[1];
  const float* ln1_g  = (const float*)d_in[2];
  const float* ln1_b  = (const float*)d_in[3];
  const float* qkv_w  = (const float*)d_in[4];
  const float* q_bias = (const float*)d_in[5];
  const float* v_bias = (const float*)d_in[6];
  const float* proj_w = (const float*)d_in[7];
  const float* proj_b = (const float*)d_in[8];
  const float* ln2_g  = (const float*)d_in[9];
  const float* ln2_b  = (const float*)d_in[10];
  const float* fc1_w  = (const float*)d_in[11];
  const float* fc1_b  = (const float*)d_in[12];
  const float* fc2_w  = (const float*)d_in[13];
  const float* fc2_b  = (const float*)d_in[14];
  const float* g1     = (const float*)d_in[15];
  const float* g2     = (const float*)d_in[16];

  char* ws = (char*)d_ws;
  uint16_t* qkvw_bf  = (uint16_t*)(ws + 0);
  uint16_t* projw_bf = (uint16_t*)(ws + 3538944);
  uint16_t* fc1w_bf  = (uint16_t*)(ws + 4718592);
  uint16_t* fc2w_bf  = (uint16_t*)(ws + 9437184);
  float*    qkvbias  = (float*)(ws + 14155776);
  uint16_t* h_bf     = (uint16_t*)(ws + 14164992);
  uint16_t* q_bf     = (uint16_t*)(ws + 20456448);
  uint16_t* km       = (uint16_t*)(ws + 26747904);
  uint16_t* vt_bf    = (uint16_t*)(ws + 33039360);
  uint16_t* po       = (uint16_t*)(ws + 39330816);
  float*    pml      = (float*)(ws + 64496640);      // ends 65283072
  int*      posbuf   = (int*)(ws + 65283072);        // 16 KB
  int*      nkbuf    = (int*)(ws + 65299456);        // 8 B
  uint16_t* o_bf     = q_bf;
  float*    x1_f     = (float*)(ws + 26747904);
  uint16_t* fc1_bf   = (uint16_t*)(ws + 39330816);
  uint16_t* h2_bf    = h_bf;

  const int M = BATCH * NSEQ;

  cvt4_kernel<<<(N_QKVW + N_PROJW + N_FC1W + N_FC2W) / 1024, 256, 0, stream>>>(
      qkv_w, proj_w, fc1_w, fc2_w, qkvw_bf, projw_bf, fc1w_bf, fc2w_bf);
  bias_kernel<<<(3 * DMODEL + 255) / 256, 256, 0, stream>>>(q_bias, v_bias, qkvbias);
  scan_kernel<<<BATCH, 256, 0, stream>>>(amask, posbuf, nkbuf);
  // zero km/vt so compacted tail tiles read exact zeros
  hipMemsetAsync(km, 0, (size_t)BATCH * NSEQ * DMODEL * 2, stream);
  hipMemsetAsync(vt_bf, 0, (size_t)BATCH * NHEAD * HDIM * NSEQ * 2, stream);

  ln_kernel<<<M, 256, 0, stream>>>(x, ln1_g, ln1_b, h_bf);
  gemm128<0><<<dim3((3 * DMODEL) / 128, M / 128), 256, 0, stream>>>(
      h_bf, qkvw_bf, qkvbias, q_bf, km, vt_bf, amask, posbuf, M, 3 * DMODEL, DMODEL);
  attn_kernel<<<dim3(BATCH * NHEAD, NSEQ / 256, NZ), 512, 0, stream>>>(
      q_bf, km, vt_bf, nkbuf, po, pml);
  merge_kernel<<<(PROWS * 8) / 256, 256, 0, stream>>>(po, pml, o_bf);
  gemm64<<<dim3(DMODEL / 64, M / 64), 256, 0, stream>>>(
      o_bf, projw_bf, proj_b, x1_f, x, g1, M, DMODEL, DMODEL);
  ln_kernel<<<M, 256, 0, stream>>>(x1_f, ln2_g, ln2_b, h2_bf);
  gemm128<2><<<dim3(HIDDEN / 128, M / 128), 256, 0, stream>>>(
      h2_bf, fc1w_bf, fc1_b, fc1_bf, nullptr, nullptr, nullptr, nullptr, M, HIDDEN, DMODEL);
  gemm64<<<dim3(DMODEL / 64, M / 64), 256, 0, stream>>>(
      fc1_bf, fc2w_bf, fc2_b, (float*)d_out, x1_f, g2, M, DMODEL, HIDDEN);
}

// Round 16
// 179.130 us; speedup vs baseline: 1.0248x; 1.0248x over previous
//
#include <hip/hip_runtime.h>
#include <hip/hip_bf16.h>
#include <stdint.h>

// ---------------- types / helpers ----------------
typedef __bf16 bf16x8 __attribute__((ext_vector_type(8)));
typedef __bf16 bf16x2 __attribute__((ext_vector_type(2)));
typedef unsigned short u16x8 __attribute__((ext_vector_type(8)));
typedef float f32x4 __attribute__((ext_vector_type(4)));
typedef float f32x16 __attribute__((ext_vector_type(16)));
typedef uint32_t u32x4 __attribute__((ext_vector_type(4)));

#define DMODEL 768
#define NSEQ   2048
#define BATCH  2
#define NHEAD  12
#define HDIM   64
#define HIDDEN 3072
#define PROWS  (BATCH * NHEAD * NSEQ)   // 49152 attention rows
#define NZ     4                        // split-KV factor
// 0.125 * log2(e): fold softmax scale AND exp->exp2 conversion into Q
#define QSCALE 0.18033688011112042f
#define MCONST 16.0f                    // constant softmax max (scores << 16)
#define PMASKED 1.52587890625e-05f      // exp2(0 - 16): each zero-pad key's P

__device__ __forceinline__ uint16_t f2bf(float f) {
  __bf16 h = (__bf16)f;
  return __builtin_bit_cast(uint16_t, h);
}
__device__ __forceinline__ float bf2f(uint16_t u) {
  uint32_t x = (uint32_t)u << 16;
  return __builtin_bit_cast(float, x);
}
__device__ __forceinline__ bf16x8 ldb8(const uint16_t* p) {
  return __builtin_bit_cast(bf16x8, *reinterpret_cast<const u16x8*>(p));
}
// tanh-form GELU via native exp2
__device__ __forceinline__ float gelu_f(float x) {
  float u = x * (1.0f + 0.044715f * x * x);
  float e = fminf(u * 2.302208545f, 80.0f);   // 2*0.79788456*log2(e)
  float t = exp2f(e);
  return x * t / (t + 1.0f);
}
// XCD-aware bijective block swizzle (nwg divisible by 8 for all launches)
__device__ __forceinline__ void xcd_swz(int& bx, int& by) {
  const int gx = gridDim.x;
  const int nwg = gx * gridDim.y;
  const int orig = blockIdx.y * gx + blockIdx.x;
  const int wg = (orig & 7) * (nwg >> 3) + (orig >> 3);
  bx = wg % gx;
  by = wg / gx;
}

using as1_void = __attribute__((address_space(1))) const void;
using as3_void = __attribute__((address_space(3))) void;
__device__ __forceinline__ void gload16(const uint16_t* src, uint16_t* lds) {
  __builtin_amdgcn_global_load_lds((as1_void*)src, (as3_void*)lds, 16, 0, 0);
}
#define MEMFENCE asm volatile("" ::: "memory")

// ---------------- fused fp32 -> bf16 casts ----------------
#define N_QKVW  (3 * DMODEL * DMODEL)
#define N_PROJW (DMODEL * DMODEL)
#define N_FC1W  (HIDDEN * DMODEL)
#define N_FC2W  (DMODEL * HIDDEN)
__global__ __launch_bounds__(256) void cvt4_kernel(const float* __restrict__ s0,
                                                   const float* __restrict__ s1,
                                                   const float* __restrict__ s2,
                                                   const float* __restrict__ s3,
                                                   uint16_t* __restrict__ d0,
                                                   uint16_t* __restrict__ d1,
                                                   uint16_t* __restrict__ d2,
                                                   uint16_t* __restrict__ d3) {
  int i4 = (blockIdx.x * 256 + threadIdx.x) * 4;
  const float* s;
  uint16_t* d;
  if (i4 < N_QKVW) { s = s0 + i4; d = d0 + i4; }
  else if (i4 < N_QKVW + N_PROJW) { int j = i4 - N_QKVW; s = s1 + j; d = d1 + j; }
  else if (i4 < N_QKVW + N_PROJW + N_FC1W) { int j = i4 - N_QKVW - N_PROJW; s = s2 + j; d = d2 + j; }
  else { int j = i4 - N_QKVW - N_PROJW - N_FC1W; s = s3 + j; d = d3 + j; }
  float4 v = *reinterpret_cast<const float4*>(s);
  ushort4 o;
  o.x = f2bf(v.x); o.y = f2bf(v.y); o.z = f2bf(v.z); o.w = f2bf(v.w);
  *reinterpret_cast<ushort4*>(d) = o;
}

// ---------------- qkv bias assembly ----------------
__global__ __launch_bounds__(256) void bias_kernel(const float* __restrict__ qb,
                                                   const float* __restrict__ vb,
                                                   float* __restrict__ out) {
  int j = blockIdx.x * 256 + threadIdx.x;
  if (j < 3 * DMODEL) {
    float v = 0.f;
    if (j < DMODEL) v = qb[j];
    else if (j >= 2 * DMODEL) v = vb[j - 2 * DMODEL];
    out[j] = v;
  }
}

// ---------------- mask prefix-sum: pos[b][n] (exclusive), nk[b] ----------------
__global__ __launch_bounds__(256) void scan_kernel(const int* __restrict__ mask,
                                                   int* __restrict__ pos,
                                                   int* __restrict__ nk) {
  const int b = blockIdx.x;
  const int tid = threadIdx.x;
  const int lane = tid & 63, w = tid >> 6;
  __shared__ int wsum[4];
  int base = 0;
  for (int c = 0; c < NSEQ; c += 256) {
    int m = (mask[b * NSEQ + c + tid] != 0);
    unsigned long long bits = __ballot(m);
    int lanepre = __popcll(bits & ((1ull << lane) - 1ull));
    if (lane == 0) wsum[w] = __popcll(bits);
    __syncthreads();
    int wpre = 0;
#pragma unroll
    for (int i = 0; i < 4; ++i) wpre += (i < w) ? wsum[i] : 0;
    pos[b * NSEQ + c + tid] = base + wpre + lanepre;
    int total = wsum[0] + wsum[1] + wsum[2] + wsum[3];
    __syncthreads();
    base += total;
  }
  if (tid == 0) nk[b] = base;
}

// ---------------- zero-tail: clear km rows / vt cols in [nk, ceil64(nk)) -------
__global__ __launch_bounds__(256) void ztail_kernel(const int* __restrict__ nk,
                                                    uint16_t* __restrict__ km,
                                                    uint16_t* __restrict__ vt) {
  const int b = blockIdx.x;
  const int NKb = nk[b];
  const int start = NKb;
  const int end = (NKb + 63) & ~63;
  const int pad = end - start;
  if (pad == 0) return;
  const int tid = blockIdx.y * 256 + threadIdx.x;
  const int nth = gridDim.y * 256;
  // km rows [start,end): pad*768 elems as 8-wide stores
  const int nkm = pad * (DMODEL / 8);
  u16x8 z = {};
  for (int i = tid; i < nkm; i += nth) {
    int r = i / (DMODEL / 8), c = (i % (DMODEL / 8)) * 8;
    *reinterpret_cast<u16x8*>(km + (size_t)(b * NSEQ + start + r) * DMODEL + c) = z;
  }
  // vt cols [start,end) for all NHEAD*HDIM rows (scalar, strided)
  const int nvt = NHEAD * HDIM * pad;
  for (int i = tid; i < nvt; i += nth) {
    int r = i / pad, c = i % pad;
    vt[((size_t)b * NHEAD * HDIM + r) * NSEQ + start + c] = 0;
  }
}

// ---------------- layernorm: fp32 in -> bf16 out ----------------
__global__ __launch_bounds__(256) void ln_kernel(const float* __restrict__ x,
                                                 const float* __restrict__ g,
                                                 const float* __restrict__ bt,
                                                 uint16_t* __restrict__ out) {
  const int row = blockIdx.x;
  const int t = threadIdx.x;
  const float* xr = x + (size_t)row * DMODEL;
  float v0 = xr[t], v1 = xr[t + 256], v2 = xr[t + 512];
  float s = v0 + v1 + v2;
  float q = v0 * v0 + v1 * v1 + v2 * v2;
  for (int off = 32; off >= 1; off >>= 1) {
    s += __shfl_xor(s, off);
    q += __shfl_xor(q, off);
  }
  __shared__ float ss[4], sq[4];
  int w = t >> 6;
  if ((t & 63) == 0) { ss[w] = s; sq[w] = q; }
  __syncthreads();
  s = ss[0] + ss[1] + ss[2] + ss[3];
  q = sq[0] + sq[1] + sq[2] + sq[3];
  const float mean = s * (1.0f / DMODEL);
  const float var = q * (1.0f / DMODEL) - mean * mean;
  const float rstd = rsqrtf(var + 1e-5f);
  uint16_t* orow = out + (size_t)row * DMODEL;
  orow[t]       = f2bf((v0 - mean) * rstd * g[t]       + bt[t]);
  orow[t + 256] = f2bf((v1 - mean) * rstd * g[t + 256] + bt[t + 256]);
  orow[t + 512] = f2bf((v2 - mean) * rstd * g[t + 512] + bt[t + 512]);
}

// ------------- GEMM A: 128x128 block, 4 waves x (64x64), dbuf counted-vmcnt ----
// XCD-swizzled blocks + T2 LDS XOR-swizzle (chunk ^= (row>>1)&3): old layout was
// an 8-way bank conflict on ds_read_b128 (row stride 16 dwords); swizzled = 2-way
// (free). Source pre-swizzled, LDS linear (gload_lds), reads use same involution.
// MODE 0: QKV gemm + fused compacting prep. MODE 2: gelu -> bf16 (fc1).
template <int MODE>
__global__ __launch_bounds__(256, 3) void gemm128(const uint16_t* __restrict__ A,
                                                  const uint16_t* __restrict__ W,
                                                  const float* __restrict__ bias,
                                                  void* __restrict__ outp,
                                                  uint16_t* __restrict__ km,
                                                  uint16_t* __restrict__ vt,
                                                  const int* __restrict__ amask,
                                                  const int* __restrict__ pos,
                                                  int M, int N, int K) {
  __shared__ uint16_t As[2][128 * 32];
  __shared__ uint16_t Bs[2][128 * 32];
  const int tid = threadIdx.x;
  const int lane = tid & 63;
  const int w = tid >> 6;
  const int wr = w >> 1, wc = w & 1;
  int bx, by;
  xcd_swz(bx, by);
  const int row0 = by * 128;
  const int col0 = bx * 128;
  const int lr = lane & 15;
  const int g = lane >> 4;

  const int o0 = w * 1024 + lane * 16;
  const int o1 = o0 + 4096;
  const int r0s = o0 >> 6;             // staging row (issue 0); issue 1 = +64
  const int r1s = o1 >> 6;
  // swizzled source chunk: (r1s>>1)&3 == (r0s>>1)&3 (rows differ by 64)
  const int sxc = (((lane & 3) ^ ((r0s >> 1) & 3)) * 8);
  const int l0 = (w * 1024) >> 1;
  const int l1 = l0 + 2048;
  const uint16_t* Abase = A + (size_t)row0 * K;
  const uint16_t* Wbase = W + (size_t)col0 * K;

  auto stage = [&](int kt) {
    uint16_t* Ad = &As[kt & 1][0];
    uint16_t* Bd = &Bs[kt & 1][0];
    const int kk = kt * 32;
    gload16(Abase + (size_t)r0s * K + kk + sxc, Ad + l0);
    gload16(Abase + (size_t)r1s * K + kk + sxc, Ad + l1);
    gload16(Wbase + (size_t)r0s * K + kk + sxc, Bd + l0);
    gload16(Wbase + (size_t)r1s * K + kk + sxc, Bd + l1);
  };

  // swizzled frag-read offset ((row>>1)&3 == (lr>>1)&3 for all frag rows)
  const int koff = (g ^ ((lr >> 1) & 3)) * 8;

  f32x4 acc[4][4] = {};
  const int nt = K >> 5;
  stage(0);
  for (int kt = 0; kt < nt; ++kt) {
    if (kt + 1 < nt) {
      stage(kt + 1);
      asm volatile("s_waitcnt vmcnt(4)" ::: "memory");
    } else {
      asm volatile("s_waitcnt vmcnt(0)" ::: "memory");
    }
    __builtin_amdgcn_s_barrier();
    MEMFENCE;
    const uint16_t* Ab = &As[kt & 1][0];
    const uint16_t* Bb = &Bs[kt & 1][0];
    bf16x8 a[4], b[4];
#pragma unroll
    for (int m = 0; m < 4; ++m) a[m] = ldb8(Ab + (wr * 64 + m * 16 + lr) * 32 + koff);
#pragma unroll
    for (int n = 0; n < 4; ++n) b[n] = ldb8(Bb + (wc * 64 + n * 16 + lr) * 32 + koff);
#pragma unroll
    for (int m = 0; m < 4; ++m)
#pragma unroll
      for (int n = 0; n < 4; ++n)
        acc[m][n] = __builtin_amdgcn_mfma_f32_16x16x32_bf16(a[m], b[n], acc[m][n], 0, 0, 0);
    MEMFENCE;
    __builtin_amdgcn_s_barrier();
  }

  if constexpr (MODE == 0) {
    const int sect = col0 / DMODEL;   // block-uniform: 0=Q, 1=K, 2=V
    const int bb = row0 >> 11;        // batch (block never crosses)
    const int* mrow = amask + bb * NSEQ;
    const int* prow = pos + bb * NSEQ;
#pragma unroll
    for (int m = 0; m < 4; ++m) {
      int row = row0 + wr * 64 + m * 16 + g * 4;
      int nn = row & 2047;
      int mk[4], ps[4];
#pragma unroll
      for (int ri = 0; ri < 4; ++ri) { mk[ri] = mrow[nn + ri]; ps[ri] = prow[nn + ri]; }
#pragma unroll
      for (int n = 0; n < 4; ++n) {
        int col = col0 + wc * 64 + n * 16 + lr;
        float bv = bias[col];
        if (sect == 0) {
#pragma unroll
          for (int ri = 0; ri < 4; ++ri)
            ((uint16_t*)outp)[(size_t)(row + ri) * DMODEL + col] =
                f2bf((acc[m][n][ri] + bv) * QSCALE);
        } else if (sect == 1) {
          int kc = col - DMODEL;
#pragma unroll
          for (int ri = 0; ri < 4; ++ri)
            if (mk[ri])
              km[(size_t)(bb * NSEQ + ps[ri]) * DMODEL + kc] = f2bf(acc[m][n][ri] + bv);
        } else {
          int vc = col - 2 * DMODEL;
          int hh2 = vc >> 6, dd = vc & 63;
          const size_t vbase = (size_t)((bb * NHEAD + hh2) * 64 + dd) * NSEQ;
#pragma unroll
          for (int ri = 0; ri < 4; ++ri)
            if (mk[ri]) vt[vbase + ps[ri]] = f2bf(acc[m][n][ri] + bv);
        }
      }
    }
  } else {
#pragma unroll
    for (int m = 0; m < 4; ++m) {
      int row = row0 + wr * 64 + m * 16 + g * 4;
#pragma unroll
      for (int n = 0; n < 4; ++n) {
        int col = col0 + wc * 64 + n * 16 + lr;
        float bv = bias[col];
#pragma unroll
        for (int ri = 0; ri < 4; ++ri) {
          float val = acc[m][n][ri] + bv;
          ((uint16_t*)outp)[(size_t)(row + ri) * N + col] = f2bf(gelu_f(val));
        }
      }
    }
  }
}

// ------------- GEMM B v2: 64x64 tile, BK=64, 4 waves, XCD-swizzled -------------
__global__ __launch_bounds__(256, 3) void gemm64(const uint16_t* __restrict__ A,
                                                 const uint16_t* __restrict__ W,
                                                 const float* __restrict__ bias,
                                                 float* __restrict__ outp,
                                                 const float* __restrict__ resid,
                                                 const float* __restrict__ gamma,
                                                 int M, int N, int K) {
  __shared__ uint16_t As[2][64 * 64];
  __shared__ uint16_t Bs[2][64 * 64];
  const int tid = threadIdx.x;
  const int lane = tid & 63;
  const int w = tid >> 6;
  const int wr = w >> 1, wc = w & 1;
  int bx, by;
  xcd_swz(bx, by);
  const int row0 = by * 64;
  const int col0 = bx * 64;
  const int lr = lane & 15;
  const int g = lane >> 4;

  const int srow = tid >> 3;
  const int schunk = tid & 7;
  const uint16_t* Abase = A + (size_t)row0 * K;
  const uint16_t* Wbase = W + (size_t)col0 * K;

  auto stage = [&](int kt) {
    uint16_t* Ad = &As[kt & 1][0];
    uint16_t* Bd = &Bs[kt & 1][0];
    const int kk = kt * 64;
#pragma unroll
    for (int i = 0; i < 2; ++i) {
      const int row = i * 32 + srow;
      const int sc = (schunk ^ (row & 7)) * 8;
      gload16(Abase + (size_t)row * K + kk + sc, Ad + i * 2048 + w * 512);
      gload16(Wbase + (size_t)row * K + kk + sc, Bd + i * 2048 + w * 512);
    }
  };

  f32x4 acc[2][2] = {};
  const int nt = K >> 6;
  stage(0);
  for (int kt = 0; kt < nt; ++kt) {
    if (kt + 1 < nt) {
      stage(kt + 1);
      asm volatile("s_waitcnt vmcnt(4)" ::: "memory");
    } else {
      asm volatile("s_waitcnt vmcnt(0)" ::: "memory");
    }
    __builtin_amdgcn_s_barrier();
    MEMFENCE;
    const uint16_t* Ab = &As[kt & 1][0];
    const uint16_t* Bb = &Bs[kt & 1][0];
#pragma unroll
    for (int kk = 0; kk < 2; ++kk) {
      bf16x8 a[2], bf[2];
#pragma unroll
      for (int m = 0; m < 2; ++m) {
        const int row = wr * 32 + m * 16 + lr;
        a[m] = ldb8(Ab + row * 64 + (((kk * 4 + g) ^ (row & 7)) * 8));
      }
#pragma unroll
      for (int n = 0; n < 2; ++n) {
        const int row = wc * 32 + n * 16 + lr;
        bf[n] = ldb8(Bb + row * 64 + (((kk * 4 + g) ^ (row & 7)) * 8));
      }
#pragma unroll
      for (int m = 0; m < 2; ++m)
#pragma unroll
        for (int n = 0; n < 2; ++n)
          acc[m][n] = __builtin_amdgcn_mfma_f32_16x16x32_bf16(a[m], bf[n], acc[m][n], 0, 0, 0);
    }
    MEMFENCE;
    __builtin_amdgcn_s_barrier();
  }

#pragma unroll
  for (int m = 0; m < 2; ++m) {
    int row = row0 + wr * 32 + m * 16 + g * 4;
#pragma unroll
    for (int n = 0; n < 2; ++n) {
      int col = col0 + wc * 32 + n * 16 + lr;
      float bv = bias[col];
      float gv = gamma[col];
#pragma unroll
      for (int ri = 0; ri < 4; ++ri) {
        float val = acc[m][n][ri] + bv;
        size_t idx = (size_t)(row + ri) * N + col;
        outp[idx] = resid[idx] + gv * val;
      }
    }
  }
}

// ---------------- flash attention v11: COMPACTED keys, quad-buffer -------------
// grid (24, 8, 4): 8 waves x 32 q-rows. Keys compacted to nk[b]; dynamic-trip
// 4-buffer pipeline, counted vmcnt. Zero-pad keys give P = 2^-16 (V = 0),
// corrected exactly via pads count. Constant-max softmax (m = 16).
__global__ __launch_bounds__(512, 4) void attn_kernel(const uint16_t* __restrict__ qb_,
                                                      const uint16_t* __restrict__ km,
                                                      const uint16_t* __restrict__ vt,
                                                      const int* __restrict__ nkarr,
                                                      uint16_t* __restrict__ po,
                                                      float* __restrict__ pml) {
  __shared__ uint16_t Kb[4][64 * 64];
  __shared__ uint16_t Vb[4][64 * 64];
  const int tid = threadIdx.x;
  const int lane = tid & 63;
  const int w = tid >> 6;            // 8 waves
  const int bh = blockIdx.x;
  const int b = bh / NHEAD, hd = bh % NHEAD;
  const int z = blockIdx.z;
  const int q0 = blockIdx.y * 256 + w * 32;
  const int l31 = lane & 31;
  const int hh = lane >> 5;

  const int NKb = nkarr[b];
  const int NTt = (NKb + 63) >> 6;          // total key tiles
  const int TPZ = (NTt + NZ - 1) >> 2;      // tiles per z-chunk
  const int s0 = (z * TPZ < NTt) ? z * TPZ : NTt;
  int e0 = s0 + TPZ; if (e0 > NTt) e0 = NTt;
  const int nt = e0 - s0;

  bf16x8 qa[4];
  const uint16_t* qptr = qb_ + (size_t)(b * NSEQ + q0 + l31) * DMODEL + hd * HDIM + hh * 8;
#pragma unroll
  for (int dblk = 0; dblk < 4; ++dblk) qa[dblk] = ldb8(qptr + dblk * 16);

  const uint16_t* kmb = km + (size_t)b * NSEQ * DMODEL + hd * HDIM;
  const uint16_t* vtb = vt + (size_t)bh * HDIM * NSEQ;

  const int srow = tid >> 3;                      // 0..63
  const int sxor = ((tid & 7) ^ (srow & 7)) * 8;  // pre-swizzled source chunk
  auto stage = [&](int t) {
    const int pb = t & 3;
    const int k0 = t * 64;
    gload16(kmb + (size_t)(k0 + srow) * DMODEL + sxor, &Kb[pb][w * 512]);
    gload16(vtb + (size_t)srow * NSEQ + k0 + sxor, &Vb[pb][w * 512]);
  };

  u16x8 ones_u;
#pragma unroll
  for (int e = 0; e < 8; ++e) ones_u[e] = 0x3F80;   // bf16 1.0
  const bf16x8 ones = __builtin_bit_cast(bf16x8, ones_u);

  f32x16 oacc[2] = {};
  f32x16 lacc = {};

  if (nt > 0) stage(s0);
  if (nt > 1) stage(s0 + 1);
  if (nt > 2) stage(s0 + 2);
  for (int i = 0; i < nt; ++i) {
    const int ahead = nt - 1 - i;
    if (ahead >= 2) {
      asm volatile("s_waitcnt vmcnt(4)" ::: "memory");
    } else if (ahead == 1) {
      asm volatile("s_waitcnt vmcnt(2)" ::: "memory");
    } else {
      asm volatile("s_waitcnt vmcnt(0)" ::: "memory");
    }
    __builtin_amdgcn_s_barrier();     // all waves' stage(s0+i) complete
    MEMFENCE;
    if (i + 3 < nt) stage(s0 + i + 3);
    const uint16_t* Kbp = &Kb[(s0 + i) & 3][0];
    const uint16_t* Vbp = &Vb[(s0 + i) & 3][0];

    // S^T[k][q] = mfma(K, Q); lane = q, regs = k
    f32x16 st[2];
    __builtin_amdgcn_s_setprio(1);
#pragma unroll
    for (int kblk = 0; kblk < 2; ++kblk) {
      f32x16 acc = {};
      const uint16_t* kr = Kbp + (kblk * 32 + l31) * 64;
#pragma unroll
      for (int dblk = 0; dblk < 4; ++dblk) {
        bf16x8 kf = ldb8(kr + ((dblk * 2 + hh) ^ (l31 & 7)) * 8);
        acc = __builtin_amdgcn_mfma_f32_32x32x16_bf16(kf, qa[dblk], acc, 0, 0, 0);
      }
      st[kblk] = acc;
    }
    __builtin_amdgcn_s_setprio(0);

    // P = exp2(s - 16), pack to bf16 pairs
    uint32_t pk[2][8];
#pragma unroll
    for (int kblk = 0; kblk < 2; ++kblk)
#pragma unroll
      for (int wn = 0; wn < 8; ++wn) {
        float e0x = exp2f(st[kblk][2 * wn] - MCONST);
        float e1x = exp2f(st[kblk][2 * wn + 1] - MCONST);
        bf16x2 pr = {(__bf16)e0x, (__bf16)e1x};
        pk[kblk][wn] = __builtin_bit_cast(uint32_t, pr);
      }

    // gather PV A-frags
    bf16x8 af[4];
#pragma unroll
    for (int kb16 = 0; kb16 < 4; ++kb16) {
      const int kblk = kb16 >> 1;
      const int a4 = (kb16 & 1) * 4;
      uint32_t ow0 = hh ? pk[kblk][a4 + 2] : pk[kblk][a4 + 0];
      uint32_t ow1 = hh ? pk[kblk][a4 + 3] : pk[kblk][a4 + 1];
      uint32_t gv0 = hh ? pk[kblk][a4 + 0] : pk[kblk][a4 + 2];
      uint32_t gv1 = hh ? pk[kblk][a4 + 1] : pk[kblk][a4 + 3];
      uint32_t sw0 = (uint32_t)__shfl_xor((int)gv0, 32);
      uint32_t sw1 = (uint32_t)__shfl_xor((int)gv1, 32);
      u32x4 afu;
      afu[0] = hh ? sw0 : ow0;
      afu[1] = hh ? sw1 : ow1;
      afu[2] = hh ? ow0 : sw0;
      afu[3] = hh ? ow1 : sw1;
      af[kb16] = __builtin_bit_cast(bf16x8, afu);
    }

    __builtin_amdgcn_s_setprio(1);
#pragma unroll
    for (int dblk = 0; dblk < 2; ++dblk) {
      const uint16_t* vr = Vbp + (dblk * 32 + l31) * 64;
#pragma unroll
      for (int kb16 = 0; kb16 < 4; ++kb16) {
        bf16x8 vf = ldb8(vr + ((kb16 * 2 + hh) ^ (l31 & 7)) * 8);
        oacc[dblk] = __builtin_amdgcn_mfma_f32_32x32x16_bf16(af[kb16], vf, oacc[dblk], 0, 0, 0);
      }
    }
#pragma unroll
    for (int kb16 = 0; kb16 < 4; ++kb16)   // row-sum on matrix pipe
      lacc = __builtin_amdgcn_mfma_f32_32x32x16_bf16(af[kb16], ones, lacc, 0, 0, 0);
    __builtin_amdgcn_s_setprio(0);
    MEMFENCE;
  }

  // zero-pad correction
  int vend = e0 * 64; if (vend > NKb) vend = NKb;
  int valid = vend - s0 * 64; if (valid < 0) valid = 0;
  const int pads = nt * 64 - valid;
  const float cntf = (float)pads * PMASKED;

  uint16_t* ob = po + ((size_t)z * PROWS + (size_t)bh * NSEQ + q0) * 64;
#pragma unroll
  for (int r = 0; r < 16; ++r) {
    const int qrow = (r & 3) + 8 * (r >> 2) + 4 * hh;
#pragma unroll
    for (int dblk = 0; dblk < 2; ++dblk)
      ob[(size_t)qrow * 64 + dblk * 32 + l31] = f2bf(oacc[dblk][r]);
  }
  if (l31 == 0) {
#pragma unroll
    for (int r = 0; r < 16; ++r) {
      const int qrow = (r & 3) + 8 * (r >> 2) + 4 * hh;
      pml[(size_t)z * PROWS + (size_t)bh * NSEQ + q0 + qrow] = lacc[r] - cntf;
    }
  }
}

// ---------------- merge 4 split-KV partials -> o_bf ----------------------------
__global__ __launch_bounds__(256) void merge_kernel(const uint16_t* __restrict__ po,
                                                    const float* __restrict__ pml,
                                                    uint16_t* __restrict__ o) {
  int gid = blockIdx.x * 256 + threadIdx.x;   // 393216 = 49152 rows x 8 chunks
  int row = gid >> 3;
  int c0 = (gid & 7) * 8;
  float L = 0.f;
#pragma unroll
  for (int zz = 0; zz < NZ; ++zz) L += pml[(size_t)zz * PROWS + row];
  float inv = L > 0.f ? 1.f / L : 0.f;
  float sum[8] = {};
#pragma unroll
  for (int zz = 0; zz < NZ; ++zz) {
    u16x8 a = *reinterpret_cast<const u16x8*>(po + ((size_t)zz * PROWS + row) * 64 + c0);
#pragma unroll
    for (int e = 0; e < 8; ++e) sum[e] += bf2f(a[e]);
  }
  int bh = row >> 11, q = row & 2047;
  int bb = bh / NHEAD, hh = bh % NHEAD;
  uint16_t* op = o + ((size_t)(bb * NSEQ + q) * DMODEL + hh * HDIM + c0);
  u16x8 outv;
#pragma unroll
  for (int e = 0; e < 8; ++e) outv[e] = f2bf(sum[e] * inv);
  *reinterpret_cast<u16x8*>(op) = outv;
}

// ---------------- host ----------------
extern "C" void kernel_launch(void* const* d_in, const int* in_sizes, int n_in,
                              void* d_out, int out_size, void* d_ws, size_t ws_size,
                              hipStream_t stream) {
  const float* x      = (const float*)d_in[0];
  const int*   amask  = (const int*)d_in[1];
  const float* ln1_g  = (const float*)d_in[2];
  const float* ln1_b  = (const float*)d_in[3];
  const float* qkv_w  = (const float*)d_in[4];
  const float* q_bias = (const float*)d_in[5];
  const float* v_bias = (const float*)d_in[6];
  const float* proj_w = (const float*)d_in[7];
  const float* proj_b = (const float*)d_in[8];
  const float* ln2_g  = (const float*)d_in[9];
  const float* ln2_b  = (const float*)d_in[10];
  const float* fc1_w  = (const float*)d_in[11];
  const float* fc1_b  = (const float*)d_in[12];
  const float* fc2_w  = (const float*)d_in[13];
  const float* fc2_b  = (const float*)d_in[14];
  const float* g1     = (const float*)d_in[15];
  const float* g2     = (const float*)d_in[16];

  char* ws = (char*)d_ws;
  uint16_t* qkvw_bf  = (uint16_t*)(ws + 0);
  uint16_t* projw_bf = (uint16_t*)(ws + 3538944);
  uint16_t* fc1w_bf  = (uint16_t*)(ws + 4718592);
  uint16_t* fc2w_bf  = (uint16_t*)(ws + 9437184);
  float*    qkvbias  = (float*)(ws + 14155776);
  uint16_t* h_bf     = (uint16_t*)(ws + 14164992);
  uint16_t* q_bf     = (uint16_t*)(ws + 20456448);
  uint16_t* km       = (uint16_t*)(ws + 26747904);
  uint16_t* vt_bf    = (uint16_t*)(ws + 33039360);
  uint16_t* po       = (uint16_t*)(ws + 39330816);
  float*    pml      = (float*)(ws + 64496640);      // ends 65283072
  int*      posbuf   = (int*)(ws + 65283072);        // 16 KB
  int*      nkbuf    = (int*)(ws + 65299456);        // 8 B
  uint16_t* o_bf     = q_bf;
  float*    x1_f     = (float*)(ws + 26747904);
  uint16_t* fc1_bf   = (uint16_t*)(ws + 39330816);
  uint16_t* h2_bf    = h_bf;

  const int M = BATCH * NSEQ;

  cvt4_kernel<<<(N_QKVW + N_PROJW + N_FC1W + N_FC2W) / 1024, 256, 0, stream>>>(
      qkv_w, proj_w, fc1_w, fc2_w, qkvw_bf, projw_bf, fc1w_bf, fc2w_bf);
  bias_kernel<<<(3 * DMODEL + 255) / 256, 256, 0, stream>>>(q_bias, v_bias, qkvbias);
  scan_kernel<<<BATCH, 256, 0, stream>>>(amask, posbuf, nkbuf);
  // zero ONLY the pad tail of km/vt (<=200 KB) -- replaces 12.6 MB runtime fills
  ztail_kernel<<<dim3(BATCH, 16), 256, 0, stream>>>(nkbuf, km, vt_bf);

  ln_kernel<<<M, 256, 0, stream>>>(x, ln1_g, ln1_b, h_bf);
  gemm128<0><<<dim3((3 * DMODEL) / 128, M / 128), 256, 0, stream>>>(
      h_bf, qkvw_bf, qkvbias, q_bf, km, vt_bf, amask, posbuf, M, 3 * DMODEL, DMODEL);
  attn_kernel<<<dim3(BATCH * NHEAD, NSEQ / 256, NZ), 512, 0, stream>>>(
      q_bf, km, vt_bf, nkbuf, po, pml);
  merge_kernel<<<(PROWS * 8) / 256, 256, 0, stream>>>(po, pml, o_bf);
  gemm64<<<dim3(DMODEL / 64, M / 64), 256, 0, stream>>>(
      o_bf, projw_bf, proj_b, x1_f, x, g1, M, DMODEL, DMODEL);
  ln_kernel<<<M, 256, 0, stream>>>(x1_f, ln2_g, ln2_b, h2_bf);
  gemm128<2><<<dim3(HIDDEN / 128, M / 128), 256, 0, stream>>>(
      h2_bf, fc1w_bf, fc1_b, fc1_bf, nullptr, nullptr, nullptr, nullptr, M, HIDDEN, DMODEL);
  gemm64<<<dim3(DMODEL / 64, M / 64), 256, 0, stream>>>(
      fc1_bf, fc2w_bf, fc2_b, (float*)d_out, x1_f, g2, M, DMODEL, HIDDEN);
}